// Round 12
// baseline (105.065 us; speedup 1.0000x reference)
//
#include <hip/hip_runtime.h>
#include <hip/hip_bf16.h>
#include <hip/hip_fp16.h>
#include <cstdint>

typedef __attribute__((ext_vector_type(8))) short short8;   // 8 bf16 (4 VGPRs)
typedef __attribute__((ext_vector_type(4))) float f32x4;

#define IN_FEAT 128
#define OUT_CH  128

// Fused edge+gemm block: waves 0-11 edge (NB=9 bins, fp32 D+I in 89KB LDS),
// waves 12-15 gemm (private 16KB T3 dbuf each, 64KB total). 155KB LDS -> 1 block/CU.
#define NBF      9
#define BINF     11136              // 9*11136 = 100224 >= N; 2*11136*4 = 89088 B
#define GEMM_LDS_OFF 89088
#define NSF_MAX  28                 // 9*28 = 252 blocks ~ 1/CU; partials 11.2MB in ws

__device__ __forceinline__ unsigned short f2bf(float f) {
    unsigned u = __float_as_uint(f);
    u += 0x7FFFu + ((u >> 16) & 1u);          // round-to-nearest-even
    return (unsigned short)(u >> 16);
}

__device__ __forceinline__ unsigned pk2(float a, float b) {
    unsigned r;
    asm("v_cvt_pk_bf16_f32 %0, %1, %2" : "=v"(r) : "v"(a), "v"(b));
    return r;
}
__device__ __forceinline__ short8 cvt8(f32x4 lo, f32x4 hi) {
    union { unsigned u[4]; short8 s8; } u;
    u.u[0] = pk2(lo[0], lo[1]);
    u.u[1] = pk2(lo[2], lo[3]);
    u.u[2] = pk2(hi[0], hi[1]);
    u.u[3] = pk2(hi[2], hi[3]);
    return u.s8;
}

__device__ __forceinline__ void gload16(const void* g, void* l) {
    __builtin_amdgcn_global_load_lds(
        (const __attribute__((address_space(1))) void*)g,
        (__attribute__((address_space(3))) void*)l, 16, 0, 0);
}

// ---- prep: Wc bf16 [256][128] (row c: W_A col c; row 128+c: W_B col c), cbias[128]
__global__ void prep_kernel(const float* __restrict__ Wk, const float* __restrict__ bk,
                            const float* __restrict__ bias, int K,
                            unsigned short* __restrict__ Wc, float* __restrict__ cbias,
                            unsigned* __restrict__ scal) {
    int idx = blockIdx.x * blockDim.x + threadIdx.x;   // 0..16383
    if (idx >= IN_FEAT * OUT_CH) return;
    int k = idx >> 7;
    int c = idx & 127;
    float va = 0.f, vb = 0.f;
    for (int kk = 0; kk < K; ++kk) {
        float w = Wk[(size_t)kk * IN_FEAT * OUT_CH + (size_t)k * OUT_CH + c];
        va += (float)(1 - kk) * w;
        vb += (float)kk * w;
    }
    Wc[(size_t)c * IN_FEAT + k]          = f2bf(va);
    Wc[(size_t)(128 + c) * IN_FEAT + k]  = f2bf(vb);
    if (idx < OUT_CH) {
        float s = bias[idx];
        for (int kk = 0; kk < K; ++kk) s += bk[kk * OUT_CH + idx];
        cbias[idx] = s;
    }
    if (idx == 0) scal[0] = 0u;        // maxdeg bits (deg >= 0)
}

// ---- FUSED: per-block, waves 0-11 run the edge bin pass (DS-atomic floor ~44-51us),
// waves 12-15 run a barrier-free per-wave T3 gemm producing tmp[A|B] bf16 in d_out.
// The two __syncthreads are outside the role split: bar1 after LDS zero, bar2 after
// {atomics || all gemm tiles}. GEMM waves never share LDS (private dbuf, per-wave
// vmcnt), so they need no internal barriers.
__global__ __launch_bounds__(1024, 4) void fused_kernel(
    const float* __restrict__ edges, const int* __restrict__ snd,
    const int* __restrict__ rcv, int E, int N, int NSr,
    __half* __restrict__ part,
    const float* __restrict__ nodes, const unsigned short* __restrict__ Wc,
    unsigned short* __restrict__ tmp, int ntwav, int nunits)
{
    __shared__ __align__(16) char smem[GEMM_LDS_OFF + 4 * 16384];   // 154,624 B
    float* ldsD = (float*)smem;
    float* ldsI = (float*)(smem + BINF * 4);

    const int tid  = threadIdx.x;
    const int lane = tid & 63;
    const int wid  = tid >> 6;
    const int l15  = lane & 15, lhi = lane >> 4;
    const bool isEdge = wid < 12;

    const int s    = blockIdx.x / NBF;       // slice (9 adjacent blocks share it)
    const int b    = blockIdx.x % NBF;       // bin
    const int node0 = b * BINF;

    // gemm constants (wave-private)
    const int unit = blockIdx.x * 4 + (wid - 12);
    const int cs   = unit & 3;               // constant col-slice (nunits % 4 == 0)
    char* wbase = smem + GEMM_LDS_OFF + (wid - 12) * 16384;

    short8 wbuf[2][2][4];
    if (isEdge) {
        f32x4 z = {0.f, 0.f, 0.f, 0.f};
        for (int i = tid; i < (2 * BINF) / 4; i += 768)
            ((f32x4*)smem)[i] = z;
    } else {
        #pragma unroll
        for (int p = 0; p < 2; ++p)
            #pragma unroll
            for (int cf = 0; cf < 2; ++cf)
                #pragma unroll
                for (int ks = 0; ks < 4; ++ks)
                    wbuf[p][cf][ks] = *(const short8*)(
                        Wc + (size_t)(p * 128 + cs * 32 + cf * 16 + l15) * IN_FEAT + ks * 32 + lhi * 8);
    }
    __syncthreads();   // bar1: LDS zero complete before any atomic

    if (isEdge) {
        const int E4  = E >> 2;
        const int per = (E4 + NSr - 1) / NSr;
        const int i0  = s * per;
        const int i1  = min(E4, i0 + per);
        const float4* e4 = (const float4*)edges;
        const int4*   s4 = (const int4*)snd;
        const int4*   r4 = (const int4*)rcv;

        for (int i = i0 + tid; i < i1; i += 768) {
            float4 w = e4[i]; int4 sd = s4[i]; int4 rc = r4[i];
            unsigned d;
            d = (unsigned)(sd.x - node0); if (d < (unsigned)BINF) atomicAdd(&ldsD[d], w.x);
            d = (unsigned)(sd.y - node0); if (d < (unsigned)BINF) atomicAdd(&ldsD[d], w.y);
            d = (unsigned)(sd.z - node0); if (d < (unsigned)BINF) atomicAdd(&ldsD[d], w.z);
            d = (unsigned)(sd.w - node0); if (d < (unsigned)BINF) atomicAdd(&ldsD[d], w.w);
            d = (unsigned)(rc.x - node0); if (d < (unsigned)BINF) atomicAdd(&ldsI[d], w.x);
            d = (unsigned)(rc.y - node0); if (d < (unsigned)BINF) atomicAdd(&ldsI[d], w.y);
            d = (unsigned)(rc.z - node0); if (d < (unsigned)BINF) atomicAdd(&ldsI[d], w.z);
            d = (unsigned)(rc.w - node0); if (d < (unsigned)BINF) atomicAdd(&ldsI[d], w.w);
        }
        if (s == NSr - 1) {
            for (int idx = (E4 << 2) + tid; idx < E; idx += 768) {
                float w = edges[idx];
                unsigned d;
                d = (unsigned)(snd[idx] - node0); if (d < (unsigned)BINF) atomicAdd(&ldsD[d], w);
                d = (unsigned)(rcv[idx] - node0); if (d < (unsigned)BINF) atomicAdd(&ldsI[d], w);
            }
        }
    } else {
        // ---- per-wave T3 gemm over 16-row x 32-col wave-tiles, no barriers ----
#define STAGEW(PB, STRIPE)                                                         \
        {                                                                          \
            int row0s = (STRIPE) * 16;                                             \
            _Pragma("unroll")                                                      \
            for (int j = 0; j < 8; ++j) {                                          \
                int row  = j * 2 + (lane >> 5);                                    \
                int pb   = (lane & 31) * 16;                                       \
                int grow = min(row0s + row, N - 1);                                \
                const char* src = (const char*)(nodes + (size_t)grow * IN_FEAT)    \
                                  + (pb ^ ((row & 7) << 4));                       \
                gload16(src, wbase + (PB) * 8192 + j * 1024);                      \
            }                                                                      \
        }
        int cur = 0;
        int wt = unit;
        if (wt < ntwav) STAGEW(0, wt >> 2)
        for (; wt < ntwav; wt += nunits) {
            const int wtn = wt + nunits;
            if (wtn < ntwav) {
                STAGEW(cur ^ 1, wtn >> 2)
                asm volatile("s_waitcnt vmcnt(8)" ::: "memory");
            } else {
                asm volatile("s_waitcnt vmcnt(0)" ::: "memory");
            }
            __builtin_amdgcn_sched_barrier(0);

            const char* base = wbase + cur * 8192;
            const int stripe = wt >> 2;
            f32x4 accA[2] = {}; f32x4 accB[2] = {};
            #pragma unroll
            for (int ks = 0; ks < 4; ++ks) {
                int r  = l15;
                int bw = ks * 128 + lhi * 32;
                int sz = (r & 7) << 4;
                f32x4 lo = *(const f32x4*)(base + r * 512 + ((bw)      ^ sz));
                f32x4 hi = *(const f32x4*)(base + r * 512 + ((bw + 16) ^ sz));
                short8 a = cvt8(lo, hi);
                #pragma unroll
                for (int cf = 0; cf < 2; ++cf) {
                    accA[cf] = __builtin_amdgcn_mfma_f32_16x16x32_bf16(wbuf[0][cf][ks], a, accA[cf], 0, 0, 0);
                    accB[cf] = __builtin_amdgcn_mfma_f32_16x16x32_bf16(wbuf[1][cf][ks], a, accB[cf], 0, 0, 0);
                }
            }
            int r = stripe * 16 + l15;
            if (r < N) {
                #pragma unroll
                for (int cf = 0; cf < 2; ++cf) {
                    int col = cs * 32 + cf * 16 + lhi * 4;
                    uint2 ua, ub;
                    ua.x = pk2(accA[cf][0], accA[cf][1]);
                    ua.y = pk2(accA[cf][2], accA[cf][3]);
                    ub.x = pk2(accB[cf][0], accB[cf][1]);
                    ub.y = pk2(accB[cf][2], accB[cf][3]);
                    *(uint2*)(tmp + (size_t)r * 256 + col)       = ua;
                    *(uint2*)(tmp + (size_t)r * 256 + 128 + col) = ub;
                }
            }
            cur ^= 1;
        }
#undef STAGEW
    }
    __syncthreads();   // bar2: atomics done (and gemm done) before partial store

    if (isEdge) {
        __half* pD = part + (size_t)(2 * s + 0) * N;
        __half* pI = part + (size_t)(2 * s + 1) * N;
        if (node0 + BINF <= N) {
            for (int i = tid; i < BINF / 4; i += 768) {
                f32x4 d = ((const f32x4*)ldsD)[i];
                f32x4 v = ((const f32x4*)ldsI)[i];
                union { __half2 h[2]; uint2 u; } ud, ui;
                ud.h[0] = __floats2half2_rn(d[0], d[1]);
                ud.h[1] = __floats2half2_rn(d[2], d[3]);
                ui.h[0] = __floats2half2_rn(v[0], v[1]);
                ui.h[1] = __floats2half2_rn(v[2], v[3]);
                *(uint2*)(pD + node0 + 4 * i) = ud.u;
                *(uint2*)(pI + node0 + 4 * i) = ui.u;
            }
        } else {
            for (int i = tid; i < BINF; i += 768) {
                int g = node0 + i;
                if (g < N) {
                    pD[g] = __float2half(ldsD[i]);
                    pI[g] = __float2half(ldsI[i]);
                }
            }
        }
    }
}

// ---- merge: net = sum_s(D_s) - sum_s(I_s) over fp16 partials; fused max(deg)
__global__ void merge_kernel(const __half* __restrict__ part, int N, int NSr,
                             float* __restrict__ net, unsigned* __restrict__ scal) {
    const int stride = gridDim.x * blockDim.x;
    const int pairs = N >> 1;
    unsigned mx = 0u;
    for (int i = blockIdx.x * blockDim.x + threadIdx.x; i < pairs; i += stride) {
        float dA = 0.f, dB = 0.f, iA = 0.f, iB = 0.f;
        for (int s = 0; s < NSr; ++s) {
            const __half2* pD = (const __half2*)(part + (size_t)(2 * s + 0) * N);
            const __half2* pI = (const __half2*)(part + (size_t)(2 * s + 1) * N);
            float2 fd = __half22float2(pD[i]);
            float2 fi = __half22float2(pI[i]);
            dA += fd.x; dB += fd.y; iA += fi.x; iB += fi.y;
        }
        ((float2*)net)[i] = make_float2(dA - iA, dB - iB);
        unsigned bA = __float_as_uint(dA), bB = __float_as_uint(dB);
        unsigned bm = bA > bB ? bA : bB;
        mx = mx > bm ? mx : bm;
    }
    if ((N & 1) && blockIdx.x == 0 && threadIdx.x == 0) {
        int g = N - 1;
        float d = 0.f, si = 0.f;
        for (int s = 0; s < NSr; ++s) {
            d  += __half2float(part[(size_t)(2 * s + 0) * N + g]);
            si += __half2float(part[(size_t)(2 * s + 1) * N + g]);
        }
        net[g] = d - si;
        unsigned bb = __float_as_uint(d);
        mx = mx > bb ? mx : bb;
    }
    #pragma unroll
    for (int off = 32; off; off >>= 1) {
        unsigned o = (unsigned)__shfl_xor((int)mx, off, 64);
        mx = mx > o ? mx : o;
    }
    if ((threadIdx.x & 63) == 0) atomicMax(&scal[0], mx);
}

// ---- combine (IN-PLACE over d_out): out[r][c] = tmpA[r][c] + s_r*tmpB[r][c] + cbias[c].
// Row handled by 16 lanes of one wave (lockstep: loads precede stores). tmp/out alias.
__global__ __launch_bounds__(512) void combine_kernel(
    const unsigned short* tmp, const float* __restrict__ net,
    const unsigned* __restrict__ scal, const float* __restrict__ cbias,
    float* out, int N)
{
    int gid0 = blockIdx.x * 512 + threadIdx.x;
    int r = gid0 >> 4, seg = gid0 & 15;
    if (r >= N) return;
    float maxd = __uint_as_float(scal[0]);
    float inv = maxd > 0.f ? 1.f / maxd : 0.f;
    float s = net[r] * inv;
    const unsigned short* rowp = tmp + (size_t)r * 256;
    short8 va = *(const short8*)(rowp + seg * 8);
    short8 vb = *(const short8*)(rowp + 128 + seg * 8);
    f32x4 c0 = *(const f32x4*)(cbias + seg * 8);
    f32x4 c1 = *(const f32x4*)(cbias + seg * 8 + 4);
    f32x4 w0, w1;
    #pragma unroll
    for (int j = 0; j < 4; ++j) {
        float a  = __uint_as_float(((unsigned)(unsigned short)va[j]) << 16);
        float bb = __uint_as_float(((unsigned)(unsigned short)vb[j]) << 16);
        w0[j] = a + s * bb + c0[j];
    }
    #pragma unroll
    for (int j = 0; j < 4; ++j) {
        float a  = __uint_as_float(((unsigned)(unsigned short)va[4 + j]) << 16);
        float bb = __uint_as_float(((unsigned)(unsigned short)vb[4 + j]) << 16);
        w1[j] = a + s * bb + c1[j];
    }
    float* po = out + (size_t)r * OUT_CH + seg * 8;
    *(f32x4*)po = w0;
    *(f32x4*)(po + 4) = w1;
}

extern "C" void kernel_launch(void* const* d_in, const int* in_sizes, int n_in,
                              void* d_out, int out_size, void* d_ws, size_t ws_size,
                              hipStream_t stream) {
    const float* nodes = (const float*)d_in[0];
    const float* edges = (const float*)d_in[1];
    const int*   snd   = (const int*)d_in[2];
    const int*   rcv   = (const int*)d_in[3];
    const float* Wk    = (const float*)d_in[4];
    const float* bk    = (const float*)d_in[5];
    const float* bias  = (const float*)d_in[6];
    float* out = (float*)d_out;

    const int N = in_sizes[0] / IN_FEAT;
    const int E = in_sizes[1];
    const int K = in_sizes[4] / (IN_FEAT * OUT_CH);

    // ws: net[N] f32 | scal | cbias | Wc | partials (NSr x {D,I} x N fp16, ~11.2MB)
    char* ws = (char*)d_ws;
    float*          net   = (float*)ws;
    size_t off = ((size_t)N * 4 + 63) & ~(size_t)63;
    unsigned*       scal  = (unsigned*)(ws + off);                   off += 64;
    float*          cbias = (float*)(ws + off);                      off += 512;
    unsigned short* Wc    = (unsigned short*)(ws + off);             off += (size_t)256 * IN_FEAT * 2;
    off = (off + 255) & ~(size_t)255;
    __half*         part  = (__half*)(ws + off);

    size_t avail = (ws_size > off) ? (ws_size - off) : 0;
    int NSr = (int)(avail / ((size_t)4 * N));   // 4B per node per slice ({D,I} fp16)
    if (NSr > NSF_MAX) NSr = NSF_MAX;
    if (NSr < 1) NSr = 1;

    // tmp [A|B] bf16 rows live in d_out; combine overwrites d_out in place.
    unsigned short* tmp = (unsigned short*)d_out;

    const int grid   = NBF * NSr;                 // 252 blocks ~ 1/CU
    const int nunits = grid * 4;                  // gemm wave-units (multiple of 4)
    const int ntwav  = ((N + 15) / 16) * 4;       // 16-row x 32-col wave-tiles

    prep_kernel<<<64, 256, 0, stream>>>(Wk, bk, bias, K, Wc, cbias, scal);
    fused_kernel<<<grid, 1024, 0, stream>>>(edges, snd, rcv, E, N, NSr, part,
                                            nodes, Wc, tmp, ntwav, nunits);
    merge_kernel<<<256, 256, 0, stream>>>(part, N, NSr, net, scal);
    combine_kernel<<<(N * 16 + 511) / 512, 512, 0, stream>>>(tmp, net, scal, cbias, out, N);
}